// Round 11
// baseline (183.147 us; speedup 1.0000x reference)
//
#include <hip/hip_runtime.h>
#include <hip/hip_bf16.h>
#include <stdint.h>

// Problem constants
#define NB 16
#define NS 4096
#define NF 256
#define NH 64
#define NEXP 16

typedef __attribute__((ext_vector_type(8))) short     bf16x8;
typedef __attribute__((ext_vector_type(4))) float     f32x4;
typedef __attribute__((ext_vector_type(2))) unsigned  u32x2;
typedef __attribute__((ext_vector_type(8))) unsigned short u16x8;

// workspace layout (bytes)
#define PART_OFF   0u          // [32][16][256] f32 partial colsums
#define GATE_OFF   524288u     // [16][16] f32 gates
#define BIASC_OFF  525312u     // [16][256] f32 combined bias
#define W1T_OFF    541696u     // [16] x 32768B : [kc8][hd64][64B]  (MFMA frag order)
#define W2T_OFF    1065984u    // [16] x 32768B : [hc8][f256][16B]  (MFMA frag order)
#define H_OFF      1590272u    // [16 e][65536 tok][64 hd] bf16 = 134217728 B
#define WS_NEED    (1590272ull + 134217728ull)

__device__ __forceinline__ unsigned short bfr(float f) {
  unsigned u = __float_as_uint(f);
  u += 0x7fffu + ((u >> 16) & 1u);
  return (unsigned short)(u >> 16);
}
__device__ __forceinline__ unsigned pk(float a, float b) {
  __hip_bfloat162 t = __float22bfloat162_rn(make_float2(a, b));
  union { __hip_bfloat162 h; unsigned u; } cv; cv.h = t; return cv.u;
}
__device__ __forceinline__ bf16x8 as_bf(f32x4 v) {
  union { f32x4 f; bf16x8 h; } u; u.f = v; return u.h;
}
__device__ __forceinline__ void stage16(const void* g, void* l) {
  __builtin_amdgcn_global_load_lds((const __attribute__((address_space(1))) void*)g,
                                   (__attribute__((address_space(3))) void*)l, 16, 0, 0);
}

// ---------------- kernel 1: colsum (blk<512) + weight prep (blk>=512) --------
__global__ void k_pre(const float* __restrict__ x, const float* __restrict__ W1,
                      const float* __restrict__ W2, uint8_t* __restrict__ wsb) {
  const int blk = blockIdx.x;
  if (blk < 512) {
    const int b  = blk >> 5;
    const int ch = blk & 31;
    const int f  = threadIdx.x;
    const float* xp = x + ((size_t)b * NS + (size_t)ch * 128) * NF + f;
    float s = 0.0f;
    for (int i = 0; i < 128; ++i) s += xp[(size_t)i * NF];
    ((float*)(wsb + PART_OFF))[(size_t)(ch * 16 + b) * NF + f] = s;
    return;
  }
  const int u = (blk - 512) * 256 + threadIdx.x;   // 0..65535 units of 16B
  u16x8 vals;
  if (u < 32768) {
    const int e  = u >> 11;
    const int r  = u & 2047;
    const int hd = r >> 5;
    const int kc = r & 31;
    const float* src = W1 + (size_t)e * (NF * NH) + (size_t)(kc * 8) * NH + hd;
#pragma unroll
    for (int j = 0; j < 8; ++j) vals[j] = bfr(src[(size_t)j * NH]);
    const int dst = (kc >> 2) * 4096 + hd * 64 + (kc & 3) * 16;
    *(u16x8*)(wsb + W1T_OFF + (size_t)e * 32768 + dst) = vals;
  } else {
    const int u2 = u - 32768;
    const int e  = u2 >> 11;
    const int r  = u2 & 2047;
    const int f  = r >> 3;
    const int hc = r & 7;
    const float* src = W2 + (size_t)e * (NH * NF) + (size_t)(hc * 8) * NF + f;
#pragma unroll
    for (int j = 0; j < 8; ++j) vals[j] = bfr(src[(size_t)j * NF]);
    const int dst = hc * 4096 + f * 16;
    *(u16x8*)(wsb + W2T_OFF + (size_t)e * 32768 + dst) = vals;
  }
}

// ---------------- kernel 2: gates + combined bias ----------------------------
__global__ void k_gate(const float* __restrict__ Wg, const float* __restrict__ bg,
                       const float* __restrict__ b2, uint8_t* __restrict__ wsb) {
  __shared__ float cs[16][256];
  __shared__ float lg[16][16];
  __shared__ float gs[16][16];
  const float* part  = (const float*)(wsb + PART_OFF);
  float* gate  = (float*)(wsb + GATE_OFF);
  float* biasc = (float*)(wsb + BIASC_OFF);
  const int t = threadIdx.x;
  for (int b = 0; b < 16; ++b) {
    float s = 0.0f;
    for (int ch = 0; ch < 32; ++ch) s += part[(size_t)(ch * 16 + b) * NF + t];
    cs[b][t] = s * (1.0f / 4096.0f);
  }
  __syncthreads();
  {
    const int b = t >> 4, e = t & 15;
    float acc = bg[e];
    for (int f = 0; f < NF; ++f) acc += cs[b][f] * Wg[f * 16 + e];
    lg[b][e] = acc;
  }
  __syncthreads();
  {
    const int b = t >> 4, e = t & 15;
    float m = lg[b][0];
    for (int j = 1; j < 16; ++j) m = fmaxf(m, lg[b][j]);
    float den = 0.0f;
    for (int j = 0; j < 16; ++j) den += __expf(lg[b][j] - m);
    float g = __expf(lg[b][e] - m) / den;
    gate[b * 16 + e] = g;
    gs[b][e] = g;
  }
  __syncthreads();
  for (int b = 0; b < 16; ++b) {
    float acc = 0.0f;
    for (int e = 0; e < 16; ++e) acc += gs[b][e] * b2[e * NF + t];
    biasc[b * NF + t] = acc;
  }
}

// ---------------- kernel 3a: GEMM1 + gelu -> h[e][tok][hd] (bf16, HBM) -------
// 512 blocks x 256 thr (4 waves); block = 128 tokens; wave = 32 tok x 64 hd.
// W1 LDS-dbuf (64KB -> 2 blocks/CU). NO gate here (independent of k_gate).
// Only barrier guards the staging dbuf; h stores are fire-and-forget.
__global__ __launch_bounds__(256, 2)
void k_h(const float* __restrict__ x, const float* __restrict__ b1g,
         const uint8_t* __restrict__ wsb, uint8_t* __restrict__ hbuf) {
  __shared__ __align__(16) uint8_t lds[65536];

  const int tid  = threadIdx.x;
  const int w    = tid >> 6;
  const int lane = tid & 63;
  const int c    = lane & 15;
  const int q    = lane >> 4;
  const int blk  = blockIdx.x;
  const int gtok0 = blk * 128 + w * 32;
  const uint8_t* w1src = wsb + W1T_OFF;

  // stage W1(0): 2048 units / 256 thr = 8 each
#pragma unroll
  for (int i = 0; i < 8; ++i)
    stage16(w1src + i * 4096 + tid * 16, lds + i * 4096 + tid * 16);

  // X preload -> bf16 B-frags (overlaps staging)
  bf16x8 xf[16];
#pragma unroll
  for (int n = 0; n < 2; ++n) {
    const float* xp = x + (size_t)(gtok0 + n * 16 + c) * NF + q * 8;
#pragma unroll
    for (int ks = 0; ks < 8; ++ks) {
      f32x4 v0 = *(const f32x4*)(xp + ks * 32);
      f32x4 v1 = *(const f32x4*)(xp + ks * 32 + 4);
      union { unsigned u[4]; bf16x8 h; } cv;
      cv.u[0] = pk(v0[0], v0[1]); cv.u[1] = pk(v0[2], v0[3]);
      cv.u[2] = pk(v1[0], v1[1]); cv.u[3] = pk(v1[2], v1[3]);
      xf[n * 8 + ks] = cv.h;
    }
  }

  __syncthreads();   // W1(0) staged

  const float K1 = -2.3021858962f;      // -2*sqrt(2/pi)*log2(e)
  const float KA = -0.102942243f;       // K1*0.044715
  const f32x4 fz = {0.0f, 0.0f, 0.0f, 0.0f};

#pragma unroll 1
  for (int e = 0; e < NEXP; ++e) {
    const int p = e & 1;
    if (e < 15) {
      const uint8_t* src = w1src + (size_t)(e + 1) * 32768;
      uint8_t* dst = lds + (p ^ 1) * 32768;
#pragma unroll
      for (int i = 0; i < 8; ++i)
        stage16(src + i * 4096 + tid * 16, dst + i * 4096 + tid * 16);
    }

    // GEMM1(e): D[hd 64][tok 32]
    const uint8_t* w1p = lds + p * 32768;
    f32x4 a1[4][2];
#pragma unroll
    for (int m = 0; m < 4; ++m) { a1[m][0] = fz; a1[m][1] = fz; }
    __builtin_amdgcn_s_setprio(1);
#pragma unroll
    for (int ks = 0; ks < 8; ++ks) {
      bf16x8 am[4];
#pragma unroll
      for (int m = 0; m < 4; ++m)
        am[m] = *(const bf16x8*)(w1p + ks * 4096 + (m * 16 + c) * 64 + q * 16);
#pragma unroll
      for (int m = 0; m < 4; ++m) {
        a1[m][0] = __builtin_amdgcn_mfma_f32_16x16x32_bf16(am[m], xf[ks],     a1[m][0], 0, 0, 0);
        a1[m][1] = __builtin_amdgcn_mfma_f32_16x16x32_bf16(am[m], xf[8 + ks], a1[m][1], 0, 0, 0);
      }
    }
    __builtin_amdgcn_s_setprio(0);

    // epilogue: bias + gelu (NO gate) -> bf16 -> h[e][tok][hd] in HBM
    uint8_t* he = hbuf + (size_t)e * 8388608;
#pragma unroll
    for (int m = 0; m < 4; ++m) {
      f32x4 b1v = *(const f32x4*)(b1g + e * NH + m * 16 + q * 4);
#pragma unroll
      for (int n = 0; n < 2; ++n) {
        f32x4 hv = a1[m][n] + b1v;
        float o[4];
#pragma unroll
        for (int r = 0; r < 4; ++r) {
          float xx = hv[r];
          float tt = fmaf(KA, xx * xx, K1);
          float ez = __builtin_amdgcn_exp2f(xx * tt);
          o[r] = xx * __builtin_amdgcn_rcpf(ez + 1.0f);
        }
        u32x2 hw;
        hw.x = pk(o[0], o[1]);
        hw.y = pk(o[2], o[3]);
        *(u32x2*)(he + (size_t)(gtok0 + n * 16 + c) * 128 + m * 32 + q * 8) = hw;
      }
    }

    __syncthreads();
  }
}

// ---------------- kernel 3b helpers ------------------------------------------
__device__ __forceinline__ void ko_loadh(bf16x8 (&h)[8], const uint8_t* hbuf, int e,
                                         int gtok0, int c, int q) {
  const uint8_t* src = hbuf + (size_t)e * 8388608 + (size_t)(gtok0 + c) * 128 + q * 16;
#pragma unroll
  for (int n2 = 0; n2 < 4; ++n2)
#pragma unroll
    for (int ks2 = 0; ks2 < 2; ++ks2)
      h[n2 * 2 + ks2] = *(const bf16x8*)(src + n2 * 2048 + ks2 * 64);
}
__device__ __forceinline__ void ko_loadw(f32x4 (&wr)[8], const uint8_t* w2src, int e,
                                         int fs, int c, int q) {
  const uint8_t* src = w2src + (size_t)e * 32768 + q * 4096 + (fs + c) * 16;
#pragma unroll
  for (int ks2 = 0; ks2 < 2; ++ks2)
#pragma unroll
    for (int m2 = 0; m2 < 4; ++m2)
      wr[ks2 * 4 + m2] = *(const f32x4*)(src + ks2 * 16384 + m2 * 256);
}
__device__ __forceinline__ void ko_mma(f32x4 (&acc)[16], const f32x4 (&wr)[8],
                                       const bf16x8 (&h)[8], float g) {
  bf16x8 ws[8];
#pragma unroll
  for (int i = 0; i < 8; ++i) {
    union { f32x4 f; unsigned u[4]; } in; in.f = wr[i];
    union { unsigned u[4]; bf16x8 h; } o;
#pragma unroll
    for (int j = 0; j < 4; ++j) {
      float lo = __uint_as_float(in.u[j] << 16) * g;
      float hi = __uint_as_float(in.u[j] & 0xffff0000u) * g;
      o.u[j] = pk(lo, hi);
    }
    ws[i] = o.h;
  }
  __builtin_amdgcn_s_setprio(1);
#pragma unroll
  for (int ks2 = 0; ks2 < 2; ++ks2)
#pragma unroll
    for (int m2 = 0; m2 < 4; ++m2)
#pragma unroll
      for (int n2 = 0; n2 < 4; ++n2)
        acc[m2 * 4 + n2] = __builtin_amdgcn_mfma_f32_16x16x32_bf16(ws[ks2 * 4 + m2], h[n2 * 2 + ks2], acc[m2 * 4 + n2], 0, 0, 0);
  __builtin_amdgcn_s_setprio(0);
}

// ---------------- kernel 3b: GEMM2 + gate-combine -> out ---------------------
// 1024 blocks x 256 thr (4 waves); block = 64 tokens; wave = 64 f x 64 tok.
// NO LDS, NO barriers: h as coalesced B-frags from HBM; W2 frags in regs
// (1-ahead double-buffer), gate folded into W2 in-register per expert.
__global__ __launch_bounds__(256, 2)
void k_o(const uint8_t* __restrict__ wsb, const uint8_t* __restrict__ hbuf,
         float* __restrict__ out) {
  const int tid  = threadIdx.x;
  const int w    = tid >> 6;
  const int lane = tid & 63;
  const int c    = lane & 15;
  const int q    = lane >> 4;
  const int blk  = blockIdx.x;
  const int gtok0 = blk * 64;
  const int b    = blk >> 6;
  const int fs   = w * 64;

  const float* gate_ws = (const float*)(wsb + GATE_OFF) + b * 16;
  const float* biasc   = (const float*)(wsb + BIASC_OFF) + b * NF;
  const uint8_t* w2src = wsb + W2T_OFF;

  const f32x4 fz = {0.0f, 0.0f, 0.0f, 0.0f};
  f32x4 acc[16];
#pragma unroll
  for (int i = 0; i < 16; ++i) acc[i] = fz;

  bf16x8 hA[8], hB[8];
  f32x4  wA[8], wB[8];

  ko_loadh(hA, hbuf, 0, gtok0, c, q);
  ko_loadw(wA, w2src, 0, fs, c, q);

#pragma unroll 1
  for (int eb = 0; eb < 8; ++eb) {
    const int e0 = 2 * eb;
    ko_loadh(hB, hbuf, e0 + 1, gtok0, c, q);
    ko_loadw(wB, w2src, e0 + 1, fs, c, q);
    ko_mma(acc, wA, hA, gate_ws[e0]);
    if (e0 + 2 < 16) {
      ko_loadh(hA, hbuf, e0 + 2, gtok0, c, q);
      ko_loadw(wA, w2src, e0 + 2, fs, c, q);
    }
    ko_mma(acc, wB, hB, gate_ws[e0 + 1]);
  }

  // store out + biasc
#pragma unroll
  for (int m2 = 0; m2 < 4; ++m2) {
    const int fbase = fs + m2 * 16 + q * 4;
    f32x4 bc = *(const f32x4*)(biasc + fbase);
#pragma unroll
    for (int n2 = 0; n2 < 4; ++n2) {
      const int token = gtok0 + n2 * 16 + c;
      f32x4 o = acc[m2 * 4 + n2] + bc;
      *(f32x4*)(out + (size_t)token * NF + fbase) = o;
    }
  }
}

// ---------------- fallback: round-6 fused kernel (used if ws too small) ------
__global__ __launch_bounds__(768, 3)
void k_main_fused(const float* __restrict__ x, const float* __restrict__ b1g,
                  const uint8_t* __restrict__ wsb, float* __restrict__ out) {
  __shared__ __align__(16) uint8_t lds[98304];
  const int tid  = threadIdx.x;
  const int w    = tid >> 6;
  const int lane = tid & 63;
  const int c    = lane & 15;
  const int q    = lane >> 4;
  const bool g1  = (w < 4);
  const int fs   = (w - 4) * 32;
  const int st   = tid - 256;
  const int blk  = blockIdx.x;
  const int b    = blk >> 5;
  const float* gate_ws = (const float*)(wsb + GATE_OFF) + b * 16;
  const float* biasc   = (const float*)(wsb + BIASC_OFF) + b * NF;
  const uint8_t* w1src = wsb + W1T_OFF;
  const uint8_t* w2src = wsb + W2T_OFF;
  const f32x4 fz = {0.0f, 0.0f, 0.0f, 0.0f};
  f32x4 R[16];
  bf16x8 w2r[2][2];
  if (!g1) {
#pragma unroll
    for (int i = 0; i < 4; ++i)
      stage16(w1src + i * 8192 + st * 16, lds + i * 8192 + st * 16);
#pragma unroll
    for (int i = 0; i < 16; ++i) R[i] = fz;
  } else {
    const int row0 = blk * 128 + w * 32;
#pragma unroll
    for (int n = 0; n < 2; ++n) {
      const float* xp = x + (size_t)(row0 + n * 16 + c) * NF + q * 8;
#pragma unroll
      for (int ks = 0; ks < 8; ++ks) {
        f32x4 v0 = *(const f32x4*)(xp + ks * 32);
        f32x4 v1 = *(const f32x4*)(xp + ks * 32 + 4);
        union { unsigned u[4]; f32x4 f; } cv;
        cv.u[0] = pk(v0[0], v0[1]); cv.u[1] = pk(v0[2], v0[3]);
        cv.u[2] = pk(v1[0], v1[1]); cv.u[3] = pk(v1[2], v1[3]);
        R[n * 8 + ks] = cv.f;
      }
    }
  }
  __syncthreads();
  const float K1 = -2.3021858962f;
  const float KA = -0.102942243f;
#pragma unroll 1
  for (int e = 0; e < NEXP; ++e) {
    const int p  = e & 1;
    const int pn = p ^ 1;
    if (g1) {
      const uint8_t* w1p = lds + p * 32768;
      f32x4 a1[4][2];
#pragma unroll
      for (int m = 0; m < 4; ++m) { a1[m][0] = fz; a1[m][1] = fz; }
      __builtin_amdgcn_s_setprio(1);
#pragma unroll
      for (int ks = 0; ks < 8; ++ks) {
        bf16x8 am[4];
#pragma unroll
        for (int m = 0; m < 4; ++m)
          am[m] = *(const bf16x8*)(w1p + ks * 4096 + (m * 16 + c) * 64 + q * 16);
#pragma unroll
        for (int m = 0; m < 4; ++m) {
          a1[m][0] = __builtin_amdgcn_mfma_f32_16x16x32_bf16(am[m], as_bf(R[ks]),     a1[m][0], 0, 0, 0);
          a1[m][1] = __builtin_amdgcn_mfma_f32_16x16x32_bf16(am[m], as_bf(R[8 + ks]), a1[m][1], 0, 0, 0);
        }
      }
      __builtin_amdgcn_s_setprio(0);
      const float gv = gate_ws[e];
      uint8_t* htp = lds + 65536 + p * 16384;
#pragma unroll
      for (int m = 0; m < 4; ++m) {
        f32x4 b1v = *(const f32x4*)(b1g + e * NH + m * 16 + q * 4);
#pragma unroll
        for (int n = 0; n < 2; ++n) {
          f32x4 hv = a1[m][n] + b1v;
          float o[4];
#pragma unroll
          for (int r = 0; r < 4; ++r) {
            float xx = hv[r];
            float tt = fmaf(KA, xx * xx, K1);
            float ez = __builtin_amdgcn_exp2f(xx * tt);
            o[r] = (gv * xx) * __builtin_amdgcn_rcpf(ez + 1.0f);
          }
          u32x2 hw;
          hw.x = pk(o[0], o[1]);
          hw.y = pk(o[2], o[3]);
          const int chunk = m * 2 + (q >> 1);
          const int tok   = w * 32 + n * 16 + c;
          *(u32x2*)(htp + chunk * 2048 + tok * 16 + (q & 1) * 8) = hw;
        }
      }
    } else {
      if (e < 15) {
        const uint8_t* src = w1src + (size_t)(e + 1) * 32768;
        uint8_t* dst = lds + pn * 32768;
#pragma unroll
        for (int i = 0; i < 4; ++i)
          stage16(src + i * 8192 + st * 16, dst + i * 8192 + st * 16);
      }
      if (e > 0) {
        const uint8_t* htp2 = lds + 65536 + pn * 16384;
        __builtin_amdgcn_s_setprio(1);
#pragma unroll
        for (int ks2 = 0; ks2 < 2; ++ks2) {
          bf16x8 bb2[8];
#pragma unroll
          for (int n2 = 0; n2 < 8; ++n2)
            bb2[n2] = *(const bf16x8*)(htp2 + (ks2 * 4 + q) * 2048 + (n2 * 16 + c) * 16);
#pragma unroll
          for (int m2 = 0; m2 < 2; ++m2)
#pragma unroll
            for (int n2 = 0; n2 < 8; ++n2)
              R[m2 * 8 + n2] = __builtin_amdgcn_mfma_f32_16x16x32_bf16(w2r[ks2][m2], bb2[n2], R[m2 * 8 + n2], 0, 0, 0);
        }
        __builtin_amdgcn_s_setprio(0);
      }
      const uint8_t* src = w2src + (size_t)e * 32768 + q * 4096 + (fs + c) * 16;
#pragma unroll
      for (int ks2 = 0; ks2 < 2; ++ks2)
#pragma unroll
        for (int m2 = 0; m2 < 2; ++m2)
          w2r[ks2][m2] = *(const bf16x8*)(src + ks2 * 16384 + m2 * 256);
    }
    __syncthreads();
  }
  if (!g1) {
    const uint8_t* htp2 = lds + 65536 + 16384;
#pragma unroll
    for (int ks2 = 0; ks2 < 2; ++ks2) {
      bf16x8 bb2[8];
#pragma unroll
      for (int n2 = 0; n2 < 8; ++n2)
        bb2[n2] = *(const bf16x8*)(htp2 + (ks2 * 4 + q) * 2048 + (n2 * 16 + c) * 16);
#pragma unroll
      for (int m2 = 0; m2 < 2; ++m2)
#pragma unroll
        for (int n2 = 0; n2 < 8; ++n2)
          R[m2 * 8 + n2] = __builtin_amdgcn_mfma_f32_16x16x32_bf16(w2r[ks2][m2], bb2[n2], R[m2 * 8 + n2], 0, 0, 0);
    }
#pragma unroll
    for (int m2 = 0; m2 < 2; ++m2) {
      const int fbase = fs + m2 * 16 + q * 4;
      f32x4 bc = *(const f32x4*)(biasc + fbase);
#pragma unroll
      for (int n2 = 0; n2 < 8; ++n2) {
        const int token = blk * 128 + n2 * 16 + c;
        f32x4 o = R[m2 * 8 + n2] + bc;
        *(f32x4*)(out + (size_t)token * NF + fbase) = o;
      }
    }
  }
}

// ---------------- host launch -------------------------------------------------
extern "C" void kernel_launch(void* const* d_in, const int* in_sizes, int n_in,
                              void* d_out, int out_size, void* d_ws, size_t ws_size,
                              hipStream_t stream) {
  const float* x  = (const float*)d_in[0];
  const float* W1 = (const float*)d_in[1];
  const float* b1 = (const float*)d_in[2];
  const float* W2 = (const float*)d_in[3];
  const float* b2 = (const float*)d_in[4];
  const float* Wg = (const float*)d_in[5];
  const float* bg = (const float*)d_in[6];
  float* out = (float*)d_out;
  uint8_t* wsb = (uint8_t*)d_ws;

  k_pre<<<768, 256, 0, stream>>>(x, W1, W2, wsb);
  k_gate<<<1, 256, 0, stream>>>(Wg, bg, b2, wsb);
  if (ws_size >= WS_NEED) {
    uint8_t* hbuf = wsb + H_OFF;
    k_h<<<512, 256, 0, stream>>>(x, b1, wsb, hbuf);
    k_o<<<1024, 256, 0, stream>>>(wsb, hbuf, out);
  } else {
    k_main_fused<<<512, 768, 0, stream>>>(x, b1, wsb, out);
  }
}

// Round 12
// 143.341 us; speedup vs baseline: 1.2777x; 1.2777x over previous
//
#include <hip/hip_runtime.h>
#include <hip/hip_bf16.h>
#include <stdint.h>

// Problem constants
#define NB 16
#define NS 4096
#define NF 256
#define NH 64
#define NEXP 16

typedef __attribute__((ext_vector_type(8))) short     bf16x8;
typedef __attribute__((ext_vector_type(4))) float     f32x4;
typedef __attribute__((ext_vector_type(4))) unsigned  u32x4;
typedef __attribute__((ext_vector_type(2))) unsigned  u32x2;
typedef __attribute__((ext_vector_type(8))) unsigned short u16x8;

// workspace layout (bytes)
#define PART_OFF   0u          // [32][16][256] f32 partial colsums
#define GATE_OFF   524288u     // [16][16] f32 gates
#define BIASC_OFF  525312u     // [16][256] f32 combined bias
#define W1T_OFF    541696u     // [16] x 32768B : [kc8][hd64][64B]  (MFMA frag order)
#define W2T_OFF    1065984u    // [16] x 32768B : [hc8][f256][16B]  (MFMA frag order)
#define H_OFF      1590272u    // h in FRAGMENT order: [e][kblk512? no: kblk][w][m][lane][16B]
                               // [16 e][512 kblk][4 w][4 m][64 lane][16B] = 134217728 B
#define WS_NEED    (1590272ull + 134217728ull)

__device__ __forceinline__ unsigned short bfr(float f) {
  unsigned u = __float_as_uint(f);
  u += 0x7fffu + ((u >> 16) & 1u);
  return (unsigned short)(u >> 16);
}
__device__ __forceinline__ unsigned pk(float a, float b) {
  __hip_bfloat162 t = __float22bfloat162_rn(make_float2(a, b));
  union { __hip_bfloat162 h; unsigned u; } cv; cv.h = t; return cv.u;
}
__device__ __forceinline__ bf16x8 as_bf(f32x4 v) {
  union { f32x4 f; bf16x8 h; } u; u.f = v; return u.h;
}
__device__ __forceinline__ void stage16(const void* g, void* l) {
  __builtin_amdgcn_global_load_lds((const __attribute__((address_space(1))) void*)g,
                                   (__attribute__((address_space(3))) void*)l, 16, 0, 0);
}

// ---------------- kernel 1: colsum (blk<512) + weight prep (blk>=512) --------
__global__ void k_pre(const float* __restrict__ x, const float* __restrict__ W1,
                      const float* __restrict__ W2, uint8_t* __restrict__ wsb) {
  const int blk = blockIdx.x;
  if (blk < 512) {
    const int b  = blk >> 5;
    const int ch = blk & 31;
    const int f  = threadIdx.x;
    const float* xp = x + ((size_t)b * NS + (size_t)ch * 128) * NF + f;
    float s = 0.0f;
    for (int i = 0; i < 128; ++i) s += xp[(size_t)i * NF];
    ((float*)(wsb + PART_OFF))[(size_t)(ch * 16 + b) * NF + f] = s;
    return;
  }
  const int u = (blk - 512) * 256 + threadIdx.x;   // 0..65535 units of 16B
  u16x8 vals;
  if (u < 32768) {
    const int e  = u >> 11;
    const int r  = u & 2047;
    const int hd = r >> 5;
    const int kc = r & 31;
    const float* src = W1 + (size_t)e * (NF * NH) + (size_t)(kc * 8) * NH + hd;
#pragma unroll
    for (int j = 0; j < 8; ++j) vals[j] = bfr(src[(size_t)j * NH]);
    const int dst = (kc >> 2) * 4096 + hd * 64 + (kc & 3) * 16;
    *(u16x8*)(wsb + W1T_OFF + (size_t)e * 32768 + dst) = vals;
  } else {
    const int u2 = u - 32768;
    const int e  = u2 >> 11;
    const int r  = u2 & 2047;
    const int f  = r >> 3;
    const int hc = r & 7;
    const float* src = W2 + (size_t)e * (NH * NF) + (size_t)(hc * 8) * NF + f;
#pragma unroll
    for (int j = 0; j < 8; ++j) vals[j] = bfr(src[(size_t)j * NF]);
    const int dst = hc * 4096 + f * 16;
    *(u16x8*)(wsb + W2T_OFF + (size_t)e * 32768 + dst) = vals;
  }
}

// ---------------- kernel 2: gates + combined bias ----------------------------
__global__ void k_gate(const float* __restrict__ Wg, const float* __restrict__ bg,
                       const float* __restrict__ b2, uint8_t* __restrict__ wsb) {
  __shared__ float cs[16][256];
  __shared__ float lg[16][16];
  __shared__ float gs[16][16];
  const float* part  = (const float*)(wsb + PART_OFF);
  float* gate  = (float*)(wsb + GATE_OFF);
  float* biasc = (float*)(wsb + BIASC_OFF);
  const int t = threadIdx.x;
  for (int b = 0; b < 16; ++b) {
    float s = 0.0f;
    for (int ch = 0; ch < 32; ++ch) s += part[(size_t)(ch * 16 + b) * NF + t];
    cs[b][t] = s * (1.0f / 4096.0f);
  }
  __syncthreads();
  {
    const int b = t >> 4, e = t & 15;
    float acc = bg[e];
    for (int f = 0; f < NF; ++f) acc += cs[b][f] * Wg[f * 16 + e];
    lg[b][e] = acc;
  }
  __syncthreads();
  {
    const int b = t >> 4, e = t & 15;
    float m = lg[b][0];
    for (int j = 1; j < 16; ++j) m = fmaxf(m, lg[b][j]);
    float den = 0.0f;
    for (int j = 0; j < 16; ++j) den += __expf(lg[b][j] - m);
    float g = __expf(lg[b][e] - m) / den;
    gate[b * 16 + e] = g;
    gs[b][e] = g;
  }
  __syncthreads();
  for (int b = 0; b < 16; ++b) {
    float acc = 0.0f;
    for (int e = 0; e < 16; ++e) acc += gs[b][e] * b2[e * NF + t];
    biasc[b * NF + t] = acc;
  }
}

// ---------------- kernel 3a: GEMM1 + gelu*gate -> h (fragment order) ---------
// 512 blocks x 256 thr (4 waves); block = 128 tokens of one batch; wave = 32 tok.
// W1 LDS-dbuf 64KB (2 blocks/CU co-resident). Gate applied here.
// h stored in MFMA D-fragment order, fully coalesced dwordx4:
//   h[e][kblk=blk][w][m][lane][16B]; lane 16B = {n0:r0r1,r2r3 | n1:r0r1,r2r3} bf16.
__global__ __launch_bounds__(256, 2)
void k_h(const float* __restrict__ x, const float* __restrict__ b1g,
         const uint8_t* __restrict__ wsb, uint8_t* __restrict__ hbuf) {
  __shared__ __align__(16) uint8_t lds[65536];

  const int tid  = threadIdx.x;
  const int w    = tid >> 6;
  const int lane = tid & 63;
  const int c    = lane & 15;
  const int q    = lane >> 4;
  const int blk  = blockIdx.x;
  const int gtok0 = blk * 128 + w * 32;
  const int b    = blk >> 5;
  const uint8_t* w1src = wsb + W1T_OFF;
  const float* gate_ws = (const float*)(wsb + GATE_OFF) + b * 16;

  // stage W1(0): 2048 units / 256 thr = 8 each
#pragma unroll
  for (int i = 0; i < 8; ++i)
    stage16(w1src + i * 4096 + tid * 16, lds + i * 4096 + tid * 16);

  // X preload -> bf16 B-frags (overlaps staging)
  bf16x8 xf[16];
#pragma unroll
  for (int n = 0; n < 2; ++n) {
    const float* xp = x + (size_t)(gtok0 + n * 16 + c) * NF + q * 8;
#pragma unroll
    for (int ks = 0; ks < 8; ++ks) {
      f32x4 v0 = *(const f32x4*)(xp + ks * 32);
      f32x4 v1 = *(const f32x4*)(xp + ks * 32 + 4);
      union { unsigned u[4]; bf16x8 h; } cv;
      cv.u[0] = pk(v0[0], v0[1]); cv.u[1] = pk(v0[2], v0[3]);
      cv.u[2] = pk(v1[0], v1[1]); cv.u[3] = pk(v1[2], v1[3]);
      xf[n * 8 + ks] = cv.h;
    }
  }

  __syncthreads();   // W1(0) staged

  const float K1 = -2.3021858962f;      // -2*sqrt(2/pi)*log2(e)
  const float KA = -0.102942243f;       // K1*0.044715
  const f32x4 fz = {0.0f, 0.0f, 0.0f, 0.0f};

#pragma unroll 1
  for (int e = 0; e < NEXP; ++e) {
    const int p = e & 1;
    if (e < 15) {
      const uint8_t* src = w1src + (size_t)(e + 1) * 32768;
      uint8_t* dst = lds + (p ^ 1) * 32768;
#pragma unroll
      for (int i = 0; i < 8; ++i)
        stage16(src + i * 4096 + tid * 16, dst + i * 4096 + tid * 16);
    }

    // GEMM1(e): D[hd 64][tok 32]
    const uint8_t* w1p = lds + p * 32768;
    f32x4 a1[4][2];
#pragma unroll
    for (int m = 0; m < 4; ++m) { a1[m][0] = fz; a1[m][1] = fz; }
    __builtin_amdgcn_s_setprio(1);
#pragma unroll
    for (int ks = 0; ks < 8; ++ks) {
      bf16x8 am[4];
#pragma unroll
      for (int m = 0; m < 4; ++m)
        am[m] = *(const bf16x8*)(w1p + ks * 4096 + (m * 16 + c) * 64 + q * 16);
#pragma unroll
      for (int m = 0; m < 4; ++m) {
        a1[m][0] = __builtin_amdgcn_mfma_f32_16x16x32_bf16(am[m], xf[ks],     a1[m][0], 0, 0, 0);
        a1[m][1] = __builtin_amdgcn_mfma_f32_16x16x32_bf16(am[m], xf[8 + ks], a1[m][1], 0, 0, 0);
      }
    }
    __builtin_amdgcn_s_setprio(0);

    // epilogue: bias + gelu*gate -> bf16 -> h fragment-order, coalesced stores
    const float gv = gate_ws[e];
    uint8_t* he = hbuf + (size_t)e * 8388608 + (size_t)blk * 16384 + w * 4096;
#pragma unroll
    for (int m = 0; m < 4; ++m) {
      f32x4 b1v = *(const f32x4*)(b1g + e * NH + m * 16 + q * 4);
      unsigned uw[4];
#pragma unroll
      for (int n = 0; n < 2; ++n) {
        f32x4 hv = a1[m][n] + b1v;
        float o[4];
#pragma unroll
        for (int r = 0; r < 4; ++r) {
          float xx = hv[r];
          float tt = fmaf(KA, xx * xx, K1);
          float ez = __builtin_amdgcn_exp2f(xx * tt);
          o[r] = (gv * xx) * __builtin_amdgcn_rcpf(ez + 1.0f);
        }
        uw[n * 2 + 0] = pk(o[0], o[1]);
        uw[n * 2 + 1] = pk(o[2], o[3]);
      }
      u32x4 sv = {uw[0], uw[1], uw[2], uw[3]};
      *(u32x4*)(he + m * 1024 + lane * 16) = sv;   // 64 lanes x 16B = 1KB coalesced
    }

    __syncthreads();
  }
}

// ---------------- kernel 3b helpers ------------------------------------------
__device__ __forceinline__ void ko_loadw(bf16x8 (&wf)[8], const uint8_t* w2src, int e,
                                         int fs, int c, int q) {
  const uint8_t* src = w2src + (size_t)e * 32768 + q * 4096 + (fs + c) * 16;
#pragma unroll
  for (int ks2 = 0; ks2 < 2; ++ks2)
#pragma unroll
    for (int m2 = 0; m2 < 4; ++m2)
      wf[ks2 * 4 + m2] = *(const bf16x8*)(src + ks2 * 16384 + m2 * 256);
}

// B-frag (tok=n2*16+c, hd=ks2*32+q*8+j) from fragment-order h chunk in LDS.
// value(tok,hd) at: (tok>>5)*4096 + (hd>>4)*1024 + (((hd>>2)&3)*16 + (tok&15))*16
//                   + ((tok>>4)&1)*8 + (hd&3)*2
__device__ __forceinline__ void ko_mma(f32x4 (&acc)[16], const bf16x8 (&wf)[8],
                                       const uint8_t* hl, int c, int q) {
#pragma unroll
  for (int ks2 = 0; ks2 < 2; ++ks2) {
    bf16x8 bb[4];
    const int m   = 2 * ks2 + (q >> 1);
    const int qlo = (q & 1) * 2;
#pragma unroll
    for (int n2 = 0; n2 < 4; ++n2) {
      const int off = (n2 >> 1) * 4096 + m * 1024 + (qlo * 16 + c) * 16 + (n2 & 1) * 8;
      u32x2 lo = *(const u32x2*)(hl + off);
      u32x2 hi = *(const u32x2*)(hl + off + 256);
      union { unsigned u[4]; bf16x8 h; } cv;
      cv.u[0] = lo.x; cv.u[1] = lo.y; cv.u[2] = hi.x; cv.u[3] = hi.y;
      bb[n2] = cv.h;
    }
    __builtin_amdgcn_s_setprio(1);
#pragma unroll
    for (int m2 = 0; m2 < 4; ++m2)
#pragma unroll
      for (int n2 = 0; n2 < 4; ++n2)
        acc[m2 * 4 + n2] = __builtin_amdgcn_mfma_f32_16x16x32_bf16(wf[ks2 * 4 + m2], bb[n2], acc[m2 * 4 + n2], 0, 0, 0);
    __builtin_amdgcn_s_setprio(0);
  }
}

// ---------------- kernel 3b: GEMM2 + combine -> out --------------------------
// 1024 blocks x 256 thr (4 waves); block = 64 tokens; wave = 64 f x 64 tok.
// h staged async into LDS dbuf (2 x 8KB); W2T bf16 frags in regs (static dbuf).
// No gate here (folded into k_h). Out = acc + biasc.
__global__ __launch_bounds__(256, 2)
void k_o(const uint8_t* __restrict__ wsb, const uint8_t* __restrict__ hbuf,
         float* __restrict__ out) {
  __shared__ __align__(16) uint8_t lds[16384];

  const int tid  = threadIdx.x;
  const int w    = tid >> 6;
  const int lane = tid & 63;
  const int c    = lane & 15;
  const int q    = lane >> 4;
  const int blk  = blockIdx.x;
  const int gtok0 = blk * 64;
  const int b    = blk >> 6;
  const int fs   = w * 64;

  const float* biasc   = (const float*)(wsb + BIASC_OFF) + b * NF;
  const uint8_t* w2src = wsb + W2T_OFF;
  const uint8_t* hsrc  = hbuf + (size_t)blk * 8192;   // + e*8388608

  const f32x4 fz = {0.0f, 0.0f, 0.0f, 0.0f};
  f32x4 acc[16];
#pragma unroll
  for (int i = 0; i < 16; ++i) acc[i] = fz;

  bf16x8 wfA[8], wfB[8];

  // prologue: stage h(0) -> buf0 ; load W2T(0)
#pragma unroll
  for (int i = 0; i < 2; ++i)
    stage16(hsrc + (tid + i * 256) * 16, lds + (tid + i * 256) * 16);
  ko_loadw(wfA, w2src, 0, fs, c, q);
  __syncthreads();

#pragma unroll 1
  for (int eb = 0; eb < 8; ++eb) {
    {
      const int e = 2 * eb;                      // uses buf0 + wfA
      const uint8_t* nsrc = hsrc + (size_t)(e + 1) * 8388608;
#pragma unroll
      for (int i = 0; i < 2; ++i)
        stage16(nsrc + (tid + i * 256) * 16, lds + 8192 + (tid + i * 256) * 16);
      ko_loadw(wfB, w2src, e + 1, fs, c, q);
      ko_mma(acc, wfA, lds, c, q);
      __syncthreads();
    }
    {
      const int e = 2 * eb + 1;                  // uses buf1 + wfB
      if (e < 15) {
        const uint8_t* nsrc = hsrc + (size_t)(e + 1) * 8388608;
#pragma unroll
        for (int i = 0; i < 2; ++i)
          stage16(nsrc + (tid + i * 256) * 16, lds + (tid + i * 256) * 16);
        ko_loadw(wfA, w2src, e + 1, fs, c, q);
      }
      ko_mma(acc, wfB, lds + 8192, c, q);
      __syncthreads();
    }
  }

  // store out + biasc
#pragma unroll
  for (int m2 = 0; m2 < 4; ++m2) {
    const int fbase = fs + m2 * 16 + q * 4;
    f32x4 bc = *(const f32x4*)(biasc + fbase);
#pragma unroll
    for (int n2 = 0; n2 < 4; ++n2) {
      const int token = gtok0 + n2 * 16 + c;
      f32x4 o = acc[m2 * 4 + n2] + bc;
      *(f32x4*)(out + (size_t)token * NF + fbase) = o;
    }
  }
}

// ---------------- fallback: round-6 fused kernel (used if ws too small) ------
__global__ __launch_bounds__(768, 3)
void k_main_fused(const float* __restrict__ x, const float* __restrict__ b1g,
                  const uint8_t* __restrict__ wsb, float* __restrict__ out) {
  __shared__ __align__(16) uint8_t lds[98304];
  const int tid  = threadIdx.x;
  const int w    = tid >> 6;
  const int lane = tid & 63;
  const int c    = lane & 15;
  const int q    = lane >> 4;
  const bool g1  = (w < 4);
  const int fs   = (w - 4) * 32;
  const int st   = tid - 256;
  const int blk  = blockIdx.x;
  const int b    = blk >> 5;
  const float* gate_ws = (const float*)(wsb + GATE_OFF) + b * 16;
  const float* biasc   = (const float*)(wsb + BIASC_OFF) + b * NF;
  const uint8_t* w1src = wsb + W1T_OFF;
  const uint8_t* w2src = wsb + W2T_OFF;
  const f32x4 fz = {0.0f, 0.0f, 0.0f, 0.0f};
  f32x4 R[16];
  bf16x8 w2r[2][2];
  if (!g1) {
#pragma unroll
    for (int i = 0; i < 4; ++i)
      stage16(w1src + i * 8192 + st * 16, lds + i * 8192 + st * 16);
#pragma unroll
    for (int i = 0; i < 16; ++i) R[i] = fz;
  } else {
    const int row0 = blk * 128 + w * 32;
#pragma unroll
    for (int n = 0; n < 2; ++n) {
      const float* xp = x + (size_t)(row0 + n * 16 + c) * NF + q * 8;
#pragma unroll
      for (int ks = 0; ks < 8; ++ks) {
        f32x4 v0 = *(const f32x4*)(xp + ks * 32);
        f32x4 v1 = *(const f32x4*)(xp + ks * 32 + 4);
        union { unsigned u[4]; f32x4 f; } cv;
        cv.u[0] = pk(v0[0], v0[1]); cv.u[1] = pk(v0[2], v0[3]);
        cv.u[2] = pk(v1[0], v1[1]); cv.u[3] = pk(v1[2], v1[3]);
        R[n * 8 + ks] = cv.f;
      }
    }
  }
  __syncthreads();
  const float K1 = -2.3021858962f;
  const float KA = -0.102942243f;
#pragma unroll 1
  for (int e = 0; e < NEXP; ++e) {
    const int p  = e & 1;
    const int pn = p ^ 1;
    if (g1) {
      const uint8_t* w1p = lds + p * 32768;
      f32x4 a1[4][2];
#pragma unroll
      for (int m = 0; m < 4; ++m) { a1[m][0] = fz; a1[m][1] = fz; }
      __builtin_amdgcn_s_setprio(1);
#pragma unroll
      for (int ks = 0; ks < 8; ++ks) {
        bf16x8 am[4];
#pragma unroll
        for (int m = 0; m < 4; ++m)
          am[m] = *(const bf16x8*)(w1p + ks * 4096 + (m * 16 + c) * 64 + q * 16);
#pragma unroll
        for (int m = 0; m < 4; ++m) {
          a1[m][0] = __builtin_amdgcn_mfma_f32_16x16x32_bf16(am[m], as_bf(R[ks]),     a1[m][0], 0, 0, 0);
          a1[m][1] = __builtin_amdgcn_mfma_f32_16x16x32_bf16(am[m], as_bf(R[8 + ks]), a1[m][1], 0, 0, 0);
        }
      }
      __builtin_amdgcn_s_setprio(0);
      const float gv = gate_ws[e];
      uint8_t* htp = lds + 65536 + p * 16384;
#pragma unroll
      for (int m = 0; m < 4; ++m) {
        f32x4 b1v = *(const f32x4*)(b1g + e * NH + m * 16 + q * 4);
#pragma unroll
        for (int n = 0; n < 2; ++n) {
          f32x4 hv = a1[m][n] + b1v;
          float o[4];
#pragma unroll
          for (int r = 0; r < 4; ++r) {
            float xx = hv[r];
            float tt = fmaf(KA, xx * xx, K1);
            float ez = __builtin_amdgcn_exp2f(xx * tt);
            o[r] = (gv * xx) * __builtin_amdgcn_rcpf(ez + 1.0f);
          }
          u32x2 hw;
          hw.x = pk(o[0], o[1]);
          hw.y = pk(o[2], o[3]);
          const int chunk = m * 2 + (q >> 1);
          const int tok   = w * 32 + n * 16 + c;
          *(u32x2*)(htp + chunk * 2048 + tok * 16 + (q & 1) * 8) = hw;
        }
      }
    } else {
      if (e < 15) {
        const uint8_t* src = w1src + (size_t)(e + 1) * 32768;
        uint8_t* dst = lds + pn * 32768;
#pragma unroll
        for (int i = 0; i < 4; ++i)
          stage16(src + i * 8192 + st * 16, dst + i * 8192 + st * 16);
      }
      if (e > 0) {
        const uint8_t* htp2 = lds + 65536 + pn * 16384;
        __builtin_amdgcn_s_setprio(1);
#pragma unroll
        for (int ks2 = 0; ks2 < 2; ++ks2) {
          bf16x8 bb2[8];
#pragma unroll
          for (int n2 = 0; n2 < 8; ++n2)
            bb2[n2] = *(const bf16x8*)(htp2 + (ks2 * 4 + q) * 2048 + (n2 * 16 + c) * 16);
#pragma unroll
          for (int m2 = 0; m2 < 2; ++m2)
#pragma unroll
            for (int n2 = 0; n2 < 8; ++n2)
              R[m2 * 8 + n2] = __builtin_amdgcn_mfma_f32_16x16x32_bf16(w2r[ks2][m2], bb2[n2], R[m2 * 8 + n2], 0, 0, 0);
        }
        __builtin_amdgcn_s_setprio(0);
      }
      const uint8_t* src = w2src + (size_t)e * 32768 + q * 4096 + (fs + c) * 16;
#pragma unroll
      for (int ks2 = 0; ks2 < 2; ++ks2)
#pragma unroll
        for (int m2 = 0; m2 < 2; ++m2)
          w2r[ks2][m2] = *(const bf16x8*)(src + ks2 * 16384 + m2 * 256);
    }
    __syncthreads();
  }
  if (!g1) {
    const uint8_t* htp2 = lds + 65536 + 16384;
#pragma unroll
    for (int ks2 = 0; ks2 < 2; ++ks2) {
      bf16x8 bb2[8];
#pragma unroll
      for (int n2 = 0; n2 < 8; ++n2)
        bb2[n2] = *(const bf16x8*)(htp2 + (ks2 * 4 + q) * 2048 + (n2 * 16 + c) * 16);
#pragma unroll
      for (int m2 = 0; m2 < 2; ++m2)
#pragma unroll
        for (int n2 = 0; n2 < 8; ++n2)
          R[m2 * 8 + n2] = __builtin_amdgcn_mfma_f32_16x16x32_bf16(w2r[ks2][m2], bb2[n2], R[m2 * 8 + n2], 0, 0, 0);
    }
#pragma unroll
    for (int m2 = 0; m2 < 2; ++m2) {
      const int fbase = fs + m2 * 16 + q * 4;
      f32x4 bc = *(const f32x4*)(biasc + fbase);
#pragma unroll
      for (int n2 = 0; n2 < 8; ++n2) {
        const int token = blk * 128 + n2 * 16 + c;
        f32x4 o = R[m2 * 8 + n2] + bc;
        *(f32x4*)(out + (size_t)token * NF + fbase) = o;
      }
    }
  }
}

// ---------------- host launch -------------------------------------------------
extern "C" void kernel_launch(void* const* d_in, const int* in_sizes, int n_in,
                              void* d_out, int out_size, void* d_ws, size_t ws_size,
                              hipStream_t stream) {
  const float* x  = (const float*)d_in[0];
  const float* W1 = (const float*)d_in[1];
  const float* b1 = (const float*)d_in[2];
  const float* W2 = (const float*)d_in[3];
  const float* b2 = (const float*)d_in[4];
  const float* Wg = (const float*)d_in[5];
  const float* bg = (const float*)d_in[6];
  float* out = (float*)d_out;
  uint8_t* wsb = (uint8_t*)d_ws;

  k_pre<<<768, 256, 0, stream>>>(x, W1, W2, wsb);
  k_gate<<<1, 256, 0, stream>>>(Wg, bg, b2, wsb);
  if (ws_size >= WS_NEED) {
    uint8_t* hbuf = wsb + H_OFF;
    k_h<<<512, 256, 0, stream>>>(x, b1, wsb, hbuf);
    k_o<<<1024, 256, 0, stream>>>(wsb, hbuf, out);
  } else {
    k_main_fused<<<512, 768, 0, stream>>>(x, b1, wsb, out);
  }
}

// Round 13
// 142.639 us; speedup vs baseline: 1.2840x; 1.0049x over previous
//
#include <hip/hip_runtime.h>
#include <hip/hip_bf16.h>
#include <stdint.h>

// Problem constants
#define NB 16
#define NS 4096
#define NF 256
#define NH 64
#define NEXP 16

typedef __attribute__((ext_vector_type(8))) short     bf16x8;
typedef __attribute__((ext_vector_type(4))) float     f32x4;
typedef __attribute__((ext_vector_type(4))) unsigned  u32x4;
typedef __attribute__((ext_vector_type(2))) unsigned  u32x2;
typedef __attribute__((ext_vector_type(8))) unsigned short u16x8;

// workspace layout (bytes)
#define PART_OFF   0u          // [32][16][256] f32 partial colsums
#define GATE_OFF   524288u     // [16][16] f32 gates
#define BIASC_OFF  525312u     // [16][256] f32 combined bias
#define W1T_OFF    541696u     // [16] x 32768B : [kc8][hd64][64B]  (MFMA frag order)
#define W2T_OFF    1065984u    // [16] x 32768B : [hc8][f256][16B]  (MFMA frag order)
#define H_OFF      1590272u    // h in FRAGMENT order: [16 e][512 kblk][4 w][4 m][64 lane][16B]
#define WS_NEED    (1590272ull + 134217728ull)

__device__ __forceinline__ unsigned short bfr(float f) {
  unsigned u = __float_as_uint(f);
  u += 0x7fffu + ((u >> 16) & 1u);
  return (unsigned short)(u >> 16);
}
__device__ __forceinline__ unsigned pk(float a, float b) {
  __hip_bfloat162 t = __float22bfloat162_rn(make_float2(a, b));
  union { __hip_bfloat162 h; unsigned u; } cv; cv.h = t; return cv.u;
}
__device__ __forceinline__ bf16x8 as_bf(f32x4 v) {
  union { f32x4 f; bf16x8 h; } u; u.f = v; return u.h;
}
__device__ __forceinline__ void stage16(const void* g, void* l) {
  __builtin_amdgcn_global_load_lds((const __attribute__((address_space(1))) void*)g,
                                   (__attribute__((address_space(3))) void*)l, 16, 0, 0);
}

// ---------------- kernel 1: colsum (blk<512) + weight prep (blk>=512) --------
__global__ void k_pre(const float* __restrict__ x, const float* __restrict__ W1,
                      const float* __restrict__ W2, uint8_t* __restrict__ wsb) {
  const int blk = blockIdx.x;
  if (blk < 512) {
    const int b  = blk >> 5;
    const int ch = blk & 31;
    const int f  = threadIdx.x;
    const float* xp = x + ((size_t)b * NS + (size_t)ch * 128) * NF + f;
    float s = 0.0f;
    for (int i = 0; i < 128; ++i) s += xp[(size_t)i * NF];
    ((float*)(wsb + PART_OFF))[(size_t)(ch * 16 + b) * NF + f] = s;
    return;
  }
  const int u = (blk - 512) * 256 + threadIdx.x;   // 0..65535 units of 16B
  u16x8 vals;
  if (u < 32768) {
    const int e  = u >> 11;
    const int r  = u & 2047;
    const int hd = r >> 5;
    const int kc = r & 31;
    const float* src = W1 + (size_t)e * (NF * NH) + (size_t)(kc * 8) * NH + hd;
#pragma unroll
    for (int j = 0; j < 8; ++j) vals[j] = bfr(src[(size_t)j * NH]);
    const int dst = (kc >> 2) * 4096 + hd * 64 + (kc & 3) * 16;
    *(u16x8*)(wsb + W1T_OFF + (size_t)e * 32768 + dst) = vals;
  } else {
    const int u2 = u - 32768;
    const int e  = u2 >> 11;
    const int r  = u2 & 2047;
    const int f  = r >> 3;
    const int hc = r & 7;
    const float* src = W2 + (size_t)e * (NH * NF) + (size_t)(hc * 8) * NF + f;
#pragma unroll
    for (int j = 0; j < 8; ++j) vals[j] = bfr(src[(size_t)j * NF]);
    const int dst = hc * 4096 + f * 16;
    *(u16x8*)(wsb + W2T_OFF + (size_t)e * 32768 + dst) = vals;
  }
}

// ---------------- kernel 2: gates + combined bias ----------------------------
__global__ void k_gate(const float* __restrict__ Wg, const float* __restrict__ bg,
                       const float* __restrict__ b2, uint8_t* __restrict__ wsb) {
  __shared__ float cs[16][256];
  __shared__ float lg[16][16];
  __shared__ float gs[16][16];
  const float* part  = (const float*)(wsb + PART_OFF);
  float* gate  = (float*)(wsb + GATE_OFF);
  float* biasc = (float*)(wsb + BIASC_OFF);
  const int t = threadIdx.x;
  for (int b = 0; b < 16; ++b) {
    float s = 0.0f;
    for (int ch = 0; ch < 32; ++ch) s += part[(size_t)(ch * 16 + b) * NF + t];
    cs[b][t] = s * (1.0f / 4096.0f);
  }
  __syncthreads();
  {
    const int b = t >> 4, e = t & 15;
    float acc = bg[e];
    for (int f = 0; f < NF; ++f) acc += cs[b][f] * Wg[f * 16 + e];
    lg[b][e] = acc;
  }
  __syncthreads();
  {
    const int b = t >> 4, e = t & 15;
    float m = lg[b][0];
    for (int j = 1; j < 16; ++j) m = fmaxf(m, lg[b][j]);
    float den = 0.0f;
    for (int j = 0; j < 16; ++j) den += __expf(lg[b][j] - m);
    float g = __expf(lg[b][e] - m) / den;
    gate[b * 16 + e] = g;
    gs[b][e] = g;
  }
  __syncthreads();
  for (int b = 0; b < 16; ++b) {
    float acc = 0.0f;
    for (int e = 0; e < 16; ++e) acc += gs[b][e] * b2[e * NF + t];
    biasc[b * NF + t] = acc;
  }
}

// ---------------- kernel 3a: GEMM1 + gelu*gate -> h (fragment order) ---------
// 512 blocks x 256 thr (4 waves); block = 128 tokens of one batch; wave = 32 tok.
// W1 LDS-dbuf 64KB (2 blocks/CU). Gate applied here. h stored in MFMA
// D-fragment order, fully coalesced dwordx4.
// Counted barrier: vmcnt(4) retires the 8 W1 stages (pinned oldest); the 4
// h-stores stay in flight across the barrier (never re-read in-kernel).
__global__ __launch_bounds__(256, 2)
void k_h(const float* __restrict__ x, const float* __restrict__ b1g,
         const uint8_t* __restrict__ wsb, uint8_t* __restrict__ hbuf) {
  __shared__ __align__(16) uint8_t lds[65536];

  const int tid  = threadIdx.x;
  const int w    = tid >> 6;
  const int lane = tid & 63;
  const int c    = lane & 15;
  const int q    = lane >> 4;
  const int blk  = blockIdx.x;
  const int gtok0 = blk * 128 + w * 32;
  const int b    = blk >> 5;
  const uint8_t* w1src = wsb + W1T_OFF;
  const float* gate_ws = (const float*)(wsb + GATE_OFF) + b * 16;

  // stage W1(0): 2048 units / 256 thr = 8 each
#pragma unroll
  for (int i = 0; i < 8; ++i)
    stage16(w1src + i * 4096 + tid * 16, lds + i * 4096 + tid * 16);

  // X preload -> bf16 B-frags (overlaps staging)
  bf16x8 xf[16];
#pragma unroll
  for (int n = 0; n < 2; ++n) {
    const float* xp = x + (size_t)(gtok0 + n * 16 + c) * NF + q * 8;
#pragma unroll
    for (int ks = 0; ks < 8; ++ks) {
      f32x4 v0 = *(const f32x4*)(xp + ks * 32);
      f32x4 v1 = *(const f32x4*)(xp + ks * 32 + 4);
      union { unsigned u[4]; bf16x8 h; } cv;
      cv.u[0] = pk(v0[0], v0[1]); cv.u[1] = pk(v0[2], v0[3]);
      cv.u[2] = pk(v1[0], v1[1]); cv.u[3] = pk(v1[2], v1[3]);
      xf[n * 8 + ks] = cv.h;
    }
  }

  __syncthreads();   // W1(0) staged (full drain once)

  const float K1 = -2.3021858962f;      // -2*sqrt(2/pi)*log2(e)
  const float KA = -0.102942243f;       // K1*0.044715
  const f32x4 fz = {0.0f, 0.0f, 0.0f, 0.0f};

#pragma unroll 1
  for (int e = 0; e < NEXP; ++e) {
    const int p = e & 1;
    if (e < 15) {
      const uint8_t* src = w1src + (size_t)(e + 1) * 32768;
      uint8_t* dst = lds + (p ^ 1) * 32768;
#pragma unroll
      for (int i = 0; i < 8; ++i)
        stage16(src + i * 4096 + tid * 16, dst + i * 4096 + tid * 16);
    }
    __builtin_amdgcn_sched_barrier(0x38F);   // VMEM may not cross: stages stay oldest

    // GEMM1(e): D[hd 64][tok 32]
    const uint8_t* w1p = lds + p * 32768;
    f32x4 a1[4][2];
#pragma unroll
    for (int m = 0; m < 4; ++m) { a1[m][0] = fz; a1[m][1] = fz; }
    __builtin_amdgcn_s_setprio(1);
#pragma unroll
    for (int ks = 0; ks < 8; ++ks) {
      bf16x8 am[4];
#pragma unroll
      for (int m = 0; m < 4; ++m)
        am[m] = *(const bf16x8*)(w1p + ks * 4096 + (m * 16 + c) * 64 + q * 16);
#pragma unroll
      for (int m = 0; m < 4; ++m) {
        a1[m][0] = __builtin_amdgcn_mfma_f32_16x16x32_bf16(am[m], xf[ks],     a1[m][0], 0, 0, 0);
        a1[m][1] = __builtin_amdgcn_mfma_f32_16x16x32_bf16(am[m], xf[8 + ks], a1[m][1], 0, 0, 0);
      }
    }
    __builtin_amdgcn_s_setprio(0);

    // epilogue: bias + gelu*gate -> bf16 -> h fragment-order, coalesced stores
    const float gv = gate_ws[e];
    uint8_t* he = hbuf + (size_t)e * 8388608 + (size_t)blk * 16384 + w * 4096;
#pragma unroll
    for (int m = 0; m < 4; ++m) {
      f32x4 b1v = *(const f32x4*)(b1g + e * NH + m * 16 + q * 4);
      unsigned uw[4];
#pragma unroll
      for (int n = 0; n < 2; ++n) {
        f32x4 hv = a1[m][n] + b1v;
        float o[4];
#pragma unroll
        for (int r = 0; r < 4; ++r) {
          float xx = hv[r];
          float tt = fmaf(KA, xx * xx, K1);
          float ez = __builtin_amdgcn_exp2f(xx * tt);
          o[r] = (gv * xx) * __builtin_amdgcn_rcpf(ez + 1.0f);
        }
        uw[n * 2 + 0] = pk(o[0], o[1]);
        uw[n * 2 + 1] = pk(o[2], o[3]);
      }
      u32x4 sv = {uw[0], uw[1], uw[2], uw[3]};
      *(u32x4*)(he + m * 1024 + lane * 16) = sv;   // 64 lanes x 16B = 1KB coalesced
    }

    // counted barrier: stages (oldest 8) retired; h-stores (newest 4) fly on
    if (e < 15) {
      asm volatile("s_waitcnt vmcnt(4) lgkmcnt(0)" ::: "memory");
      __builtin_amdgcn_s_barrier();
      __builtin_amdgcn_sched_barrier(0);
    }
  }
}

// ---------------- kernel 3b helpers ------------------------------------------
__device__ __forceinline__ void ko_loadw(bf16x8 (&wf)[8], const uint8_t* w2src, int e,
                                         int fs, int c, int q) {
  const uint8_t* src = w2src + (size_t)e * 32768 + q * 4096 + (fs + c) * 16;
#pragma unroll
  for (int ks2 = 0; ks2 < 2; ++ks2)
#pragma unroll
    for (int m2 = 0; m2 < 4; ++m2)
      wf[ks2 * 4 + m2] = *(const bf16x8*)(src + ks2 * 16384 + m2 * 256);
}

// B-frag (tok=n2*16+c, hd=ks2*32+q*8+j) from fragment-order h chunk in LDS.
__device__ __forceinline__ void ko_mma(f32x4 (&acc)[16], const bf16x8 (&wf)[8],
                                       const uint8_t* hl, int c, int q) {
#pragma unroll
  for (int ks2 = 0; ks2 < 2; ++ks2) {
    bf16x8 bb[4];
    const int m   = 2 * ks2 + (q >> 1);
    const int qlo = (q & 1) * 2;
#pragma unroll
    for (int n2 = 0; n2 < 4; ++n2) {
      const int off = (n2 >> 1) * 4096 + m * 1024 + (qlo * 16 + c) * 16 + (n2 & 1) * 8;
      u32x2 lo = *(const u32x2*)(hl + off);
      u32x2 hi = *(const u32x2*)(hl + off + 256);
      union { unsigned u[4]; bf16x8 h; } cv;
      cv.u[0] = lo.x; cv.u[1] = lo.y; cv.u[2] = hi.x; cv.u[3] = hi.y;
      bb[n2] = cv.h;
    }
    __builtin_amdgcn_s_setprio(1);
#pragma unroll
    for (int m2 = 0; m2 < 4; ++m2)
#pragma unroll
      for (int n2 = 0; n2 < 4; ++n2)
        acc[m2 * 4 + n2] = __builtin_amdgcn_mfma_f32_16x16x32_bf16(wf[ks2 * 4 + m2], bb[n2], acc[m2 * 4 + n2], 0, 0, 0);
    __builtin_amdgcn_s_setprio(0);
  }
}

// ---------------- kernel 3b: GEMM2 + combine -> out --------------------------
// 1024 blocks x 256 thr (4 waves, ~3 blocks/CU); block = 64 tokens; wave = 64f x 64tok.
// h staged async into LDS dbuf (2 x 8KB); W2T bf16 frags in regs (static dbuf).
// Counted barrier: vmcnt(8) retires the 2 h-stages (pinned oldest); the 8 W2
// frag-loads stay in flight (compiler waits before their MFMA use).
__global__ __launch_bounds__(256, 3)
void k_o(const uint8_t* __restrict__ wsb, const uint8_t* __restrict__ hbuf,
         float* __restrict__ out) {
  __shared__ __align__(16) uint8_t lds[16384];

  const int tid  = threadIdx.x;
  const int w    = tid >> 6;
  const int lane = tid & 63;
  const int c    = lane & 15;
  const int q    = lane >> 4;
  const int blk  = blockIdx.x;
  const int gtok0 = blk * 64;
  const int b    = blk >> 6;
  const int fs   = w * 64;

  const float* biasc   = (const float*)(wsb + BIASC_OFF) + b * NF;
  const uint8_t* w2src = wsb + W2T_OFF;
  const uint8_t* hsrc  = hbuf + (size_t)blk * 8192;   // + e*8388608

  const f32x4 fz = {0.0f, 0.0f, 0.0f, 0.0f};
  f32x4 acc[16];
#pragma unroll
  for (int i = 0; i < 16; ++i) acc[i] = fz;

  bf16x8 wfA[8], wfB[8];

  // prologue: stage h(0) -> buf0 ; load W2T(0)
#pragma unroll
  for (int i = 0; i < 2; ++i)
    stage16(hsrc + (tid + i * 256) * 16, lds + (tid + i * 256) * 16);
  ko_loadw(wfA, w2src, 0, fs, c, q);
  __syncthreads();

#pragma unroll 1
  for (int eb = 0; eb < 8; ++eb) {
    {
      const int e = 2 * eb;                      // uses buf0 + wfA
      const uint8_t* nsrc = hsrc + (size_t)(e + 1) * 8388608;
#pragma unroll
      for (int i = 0; i < 2; ++i)
        stage16(nsrc + (tid + i * 256) * 16, lds + 8192 + (tid + i * 256) * 16);
      __builtin_amdgcn_sched_barrier(0x38F);     // stages stay oldest VMEM
      ko_loadw(wfB, w2src, e + 1, fs, c, q);
      ko_mma(acc, wfA, lds, c, q);
      asm volatile("s_waitcnt vmcnt(8) lgkmcnt(0)" ::: "memory");
      __builtin_amdgcn_s_barrier();
      __builtin_amdgcn_sched_barrier(0);
    }
    {
      const int e = 2 * eb + 1;                  // uses buf1 + wfB
      if (e < 15) {
        const uint8_t* nsrc = hsrc + (size_t)(e + 1) * 8388608;
#pragma unroll
        for (int i = 0; i < 2; ++i)
          stage16(nsrc + (tid + i * 256) * 16, lds + (tid + i * 256) * 16);
        __builtin_amdgcn_sched_barrier(0x38F);
        ko_loadw(wfA, w2src, e + 1, fs, c, q);
      }
      ko_mma(acc, wfB, lds + 8192, c, q);
      if (e < 15) {
        asm volatile("s_waitcnt vmcnt(8) lgkmcnt(0)" ::: "memory");
        __builtin_amdgcn_s_barrier();
        __builtin_amdgcn_sched_barrier(0);
      }
    }
  }

  // store out + biasc
#pragma unroll
  for (int m2 = 0; m2 < 4; ++m2) {
    const int fbase = fs + m2 * 16 + q * 4;
    f32x4 bc = *(const f32x4*)(biasc + fbase);
#pragma unroll
    for (int n2 = 0; n2 < 4; ++n2) {
      const int token = gtok0 + n2 * 16 + c;
      f32x4 o = acc[m2 * 4 + n2] + bc;
      *(f32x4*)(out + (size_t)token * NF + fbase) = o;
    }
  }
}

// ---------------- fallback: round-6 fused kernel (used if ws too small) ------
__global__ __launch_bounds__(768, 3)
void k_main_fused(const float* __restrict__ x, const float* __restrict__ b1g,
                  const uint8_t* __restrict__ wsb, float* __restrict__ out) {
  __shared__ __align__(16) uint8_t lds[98304];
  const int tid  = threadIdx.x;
  const int w    = tid >> 6;
  const int lane = tid & 63;
  const int c    = lane & 15;
  const int q    = lane >> 4;
  const bool g1  = (w < 4);
  const int fs   = (w - 4) * 32;
  const int st   = tid - 256;
  const int blk  = blockIdx.x;
  const int b    = blk >> 5;
  const float* gate_ws = (const float*)(wsb + GATE_OFF) + b * 16;
  const float* biasc   = (const float*)(wsb + BIASC_OFF) + b * NF;
  const uint8_t* w1src = wsb + W1T_OFF;
  const uint8_t* w2src = wsb + W2T_OFF;
  const f32x4 fz = {0.0f, 0.0f, 0.0f, 0.0f};
  f32x4 R[16];
  bf16x8 w2r[2][2];
  if (!g1) {
#pragma unroll
    for (int i = 0; i < 4; ++i)
      stage16(w1src + i * 8192 + st * 16, lds + i * 8192 + st * 16);
#pragma unroll
    for (int i = 0; i < 16; ++i) R[i] = fz;
  } else {
    const int row0 = blk * 128 + w * 32;
#pragma unroll
    for (int n = 0; n < 2; ++n) {
      const float* xp = x + (size_t)(row0 + n * 16 + c) * NF + q * 8;
#pragma unroll
      for (int ks = 0; ks < 8; ++ks) {
        f32x4 v0 = *(const f32x4*)(xp + ks * 32);
        f32x4 v1 = *(const f32x4*)(xp + ks * 32 + 4);
        union { unsigned u[4]; f32x4 f; } cv;
        cv.u[0] = pk(v0[0], v0[1]); cv.u[1] = pk(v0[2], v0[3]);
        cv.u[2] = pk(v1[0], v1[1]); cv.u[3] = pk(v1[2], v1[3]);
        R[n * 8 + ks] = cv.f;
      }
    }
  }
  __syncthreads();
  const float K1 = -2.3021858962f;
  const float KA = -0.102942243f;
#pragma unroll 1
  for (int e = 0; e < NEXP; ++e) {
    const int p  = e & 1;
    const int pn = p ^ 1;
    if (g1) {
      const uint8_t* w1p = lds + p * 32768;
      f32x4 a1[4][2];
#pragma unroll
      for (int m = 0; m < 4; ++m) { a1[m][0] = fz; a1[m][1] = fz; }
      __builtin_amdgcn_s_setprio(1);
#pragma unroll
      for (int ks = 0; ks < 8; ++ks) {
        bf16x8 am[4];
#pragma unroll
        for (int m = 0; m < 4; ++m)
          am[m] = *(const bf16x8*)(w1p + ks * 4096 + (m * 16 + c) * 64 + q * 16);
#pragma unroll
        for (int m = 0; m < 4; ++m) {
          a1[m][0] = __builtin_amdgcn_mfma_f32_16x16x32_bf16(am[m], as_bf(R[ks]),     a1[m][0], 0, 0, 0);
          a1[m][1] = __builtin_amdgcn_mfma_f32_16x16x32_bf16(am[m], as_bf(R[8 + ks]), a1[m][1], 0, 0, 0);
        }
      }
      __builtin_amdgcn_s_setprio(0);
      const float gv = gate_ws[e];
      uint8_t* htp = lds + 65536 + p * 16384;
#pragma unroll
      for (int m = 0; m < 4; ++m) {
        f32x4 b1v = *(const f32x4*)(b1g + e * NH + m * 16 + q * 4);
#pragma unroll
        for (int n = 0; n < 2; ++n) {
          f32x4 hv = a1[m][n] + b1v;
          float o[4];
#pragma unroll
          for (int r = 0; r < 4; ++r) {
            float xx = hv[r];
            float tt = fmaf(KA, xx * xx, K1);
            float ez = __builtin_amdgcn_exp2f(xx * tt);
            o[r] = (gv * xx) * __builtin_amdgcn_rcpf(ez + 1.0f);
          }
          u32x2 hw;
          hw.x = pk(o[0], o[1]);
          hw.y = pk(o[2], o[3]);
          const int chunk = m * 2 + (q >> 1);
          const int tok   = w * 32 + n * 16 + c;
          *(u32x2*)(htp + chunk * 2048 + tok * 16 + (q & 1) * 8) = hw;
        }
      }
    } else {
      if (e < 15) {
        const uint8_t* src = w1src + (size_t)(e + 1) * 32768;
        uint8_t* dst = lds + pn * 32768;
#pragma unroll
        for (int i = 0; i < 4; ++i)
          stage16(src + i * 8192 + st * 16, dst + i * 8192 + st * 16);
      }
      if (e > 0) {
        const uint8_t* htp2 = lds + 65536 + pn * 16384;
        __builtin_amdgcn_s_setprio(1);
#pragma unroll
        for (int ks2 = 0; ks2 < 2; ++ks2) {
          bf16x8 bb2[8];
#pragma unroll
          for (int n2 = 0; n2 < 8; ++n2)
            bb2[n2] = *(const bf16x8*)(htp2 + (ks2 * 4 + q) * 2048 + (n2 * 16 + c) * 16);
#pragma unroll
          for (int m2 = 0; m2 < 2; ++m2)
#pragma unroll
            for (int n2 = 0; n2 < 8; ++n2)
              R[m2 * 8 + n2] = __builtin_amdgcn_mfma_f32_16x16x32_bf16(w2r[ks2][m2], bb2[n2], R[m2 * 8 + n2], 0, 0, 0);
        }
        __builtin_amdgcn_s_setprio(0);
      }
      const uint8_t* src = w2src + (size_t)e * 32768 + q * 4096 + (fs + c) * 16;
#pragma unroll
      for (int ks2 = 0; ks2 < 2; ++ks2)
#pragma unroll
        for (int m2 = 0; m2 < 2; ++m2)
          w2r[ks2][m2] = *(const bf16x8*)(src + ks2 * 16384 + m2 * 256);
    }
    __syncthreads();
  }
  if (!g1) {
    const uint8_t* htp2 = lds + 65536 + 16384;
#pragma unroll
    for (int ks2 = 0; ks2 < 2; ++ks2) {
      bf16x8 bb2[8];
#pragma unroll
      for (int n2 = 0; n2 < 8; ++n2)
        bb2[n2] = *(const bf16x8*)(htp2 + (ks2 * 4 + q) * 2048 + (n2 * 16 + c) * 16);
#pragma unroll
      for (int m2 = 0; m2 < 2; ++m2)
#pragma unroll
        for (int n2 = 0; n2 < 8; ++n2)
          R[m2 * 8 + n2] = __builtin_amdgcn_mfma_f32_16x16x32_bf16(w2r[ks2][m2], bb2[n2], R[m2 * 8 + n2], 0, 0, 0);
    }
#pragma unroll
    for (int m2 = 0; m2 < 2; ++m2) {
      const int fbase = fs + m2 * 16 + q * 4;
      f32x4 bc = *(const f32x4*)(biasc + fbase);
#pragma unroll
      for (int n2 = 0; n2 < 8; ++n2) {
        const int token = blk * 128 + n2 * 16 + c;
        f32x4 o = R[m2 * 8 + n2] + bc;
        *(f32x4*)(out + (size_t)token * NF + fbase) = o;
      }
    }
  }
}

// ---------------- host launch -------------------------------------------------
extern "C" void kernel_launch(void* const* d_in, const int* in_sizes, int n_in,
                              void* d_out, int out_size, void* d_ws, size_t ws_size,
                              hipStream_t stream) {
  const float* x  = (const float*)d_in[0];
  const float* W1 = (const float*)d_in[1];
  const float* b1 = (const float*)d_in[2];
  const float* W2 = (const float*)d_in[3];
  const float* b2 = (const float*)d_in[4];
  const float* Wg = (const float*)d_in[5];
  const float* bg = (const float*)d_in[6];
  float* out = (float*)d_out;
  uint8_t* wsb = (uint8_t*)d_ws;

  k_pre<<<768, 256, 0, stream>>>(x, W1, W2, wsb);
  k_gate<<<1, 256, 0, stream>>>(Wg, bg, b2, wsb);
  if (ws_size >= WS_NEED) {
    uint8_t* hbuf = wsb + H_OFF;
    k_h<<<512, 256, 0, stream>>>(x, b1, wsb, hbuf);
    k_o<<<1024, 256, 0, stream>>>(wsb, hbuf, out);
  } else {
    k_main_fused<<<512, 768, 0, stream>>>(x, b1, wsb, out);
  }
}